// Round 2
// baseline (535.650 us; speedup 1.0000x reference)
//
#include <hip/hip_runtime.h>
#include <stdint.h>

#define NN 100000
#define NE 1600000
#define CH 128
#define OC 64
#define NG 512
#define NBLK 256      // partition blocks
#define NBMAX 4096    // max coarse buckets (nodes/256)
#define POOLB 400     // pool blocks
#define PADSLACK 1792 // per-bucket ssrc padding slack: 256 nodes * 7

typedef unsigned int uint;
typedef unsigned short ushort;
typedef __attribute__((ext_vector_type(8))) short short8;
typedef __attribute__((ext_vector_type(4))) float floatx4;

__device__ __forceinline__ ushort f2bf(float f) {
    uint u = __float_as_uint(f);
    uint r = u + 0x7fffu + ((u >> 16) & 1u);  // round-to-nearest-even
    return (ushort)(r >> 16);
}
__device__ __forceinline__ float bf_lo(uint g) { return __uint_as_float(g << 16); }
__device__ __forceinline__ float bf_hi(uint g) { return __uint_as_float(g & 0xffff0000u); }

// ---------------- bucket histogram, written bucket-major ----------------
__global__ __launch_bounds__(256) void k_hist(const int* __restrict__ dst,
                                              int* __restrict__ bhT,
                                              int E, int NB, int chunk) {
    __shared__ int h[NBMAX];
    int blk = blockIdx.x, tid = threadIdx.x;
    for (int j = tid; j < NB; j += 256) h[j] = 0;
    __syncthreads();
    int lo = blk * chunk, hi = min(E, lo + chunk);
    for (int i = lo + tid; i < hi; i += 256) atomicAdd(&h[dst[i] >> 8], 1);
    __syncthreads();
    for (int j = tid; j < NB; j += 256) bhT[j * NBLK + blk] = h[j];
}

// ---------------- prefix scan (2-phase; block offsets folded by consumers) ---
__global__ __launch_bounds__(256) void k_scan1(const int* __restrict__ in,
                                               int* __restrict__ excl,
                                               int* __restrict__ bsums, int T) {
    __shared__ int sd[256];
    int tid = threadIdx.x;
    int base = blockIdx.x * 1024 + tid * 4;
    int v[4];
#pragma unroll
    for (int i = 0; i < 4; i++) v[i] = (base + i < T) ? in[base + i] : 0;
    int tsum = v[0] + v[1] + v[2] + v[3];
    int val = tsum;
    sd[tid] = val; __syncthreads();
    for (int off = 1; off < 256; off <<= 1) {
        int t = (tid >= off) ? sd[tid - off] : 0;
        __syncthreads();
        val += t; sd[tid] = val;
        __syncthreads();
    }
    int run = val - tsum;
#pragma unroll
    for (int i = 0; i < 4; i++) {
        if (base + i < T) excl[base + i] = run;
        run += v[i];
    }
    if (tid == 255) bsums[blockIdx.x] = val;
}

__global__ __launch_bounds__(128) void k_scan2(int* __restrict__ bs, int nb) {
    __shared__ int sd[128];
    int tid = threadIdx.x;
    int v = (tid < nb) ? bs[tid] : 0;
    int val = v;
    sd[tid] = val; __syncthreads();
    for (int off = 1; off < 128; off <<= 1) {
        int t = (tid >= off) ? sd[tid - off] : 0;
        __syncthreads();
        val += t; sd[tid] = val;
        __syncthreads();
    }
    if (tid < nb) bs[tid] = val - v;
}

// ------- partition: packed (src<<8)|(dst&255) into per-(bucket,block) segs ----
__global__ __launch_bounds__(256) void k_part(const int* __restrict__ src,
                                              const int* __restrict__ dst,
                                              const int* __restrict__ off,
                                              const int* __restrict__ boff,
                                              int* __restrict__ ebuf,
                                              int E, int NB, int chunk) {
    __shared__ int cur[NBMAX];
    int blk = blockIdx.x, tid = threadIdx.x;
    for (int j = tid; j < NB; j += 256) {
        int idx = j * NBLK + blk;
        cur[j] = off[idx] + boff[idx >> 10];
    }
    __syncthreads();
    int lo = blk * chunk, hi = min(E, lo + chunk);
    for (int i = lo + tid; i < hi; i += 256) {
        int s = src[i], d = dst[i];
        int pos = atomicAdd(&cur[d >> 8], 1);
        ebuf[pos] = (s << 8) | (d & 255);
    }
}

// ------- CSR finalize per bucket: deg, dinv, row_start, padded scatter -------
// Rows padded to multiple of 8; pad slots & inter-bucket gaps filled with the
// sentinel node index n (whose feature row is all zeros).
__global__ __launch_bounds__(256) void k_csr(const int* __restrict__ ebuf,
                                             const int* __restrict__ off,
                                             const int* __restrict__ boff,
                                             int* __restrict__ row_start,
                                             float* __restrict__ dinv,
                                             int* __restrict__ ssrc,
                                             int n, int NB, int E) {
    __shared__ int cnt[256], sc[256], cur[256];
    int b = blockIdx.x, tid = threadIdx.x;
    int node0 = b << 8;
    int i0 = b * NBLK;
    int bstart = off[i0] + boff[i0 >> 10];
    int bend = E;
    if (b + 1 < NB) {
        int i1 = (b + 1) * NBLK;
        bend = off[i1] + boff[i1 >> 10];
    }
    // padded ssrc region for this bucket
    int rbeg = bstart + b * PADSLACK;
    int rend = bend + (b + 1) * PADSLACK;
    cnt[tid] = 0;
    __syncthreads();
    for (int i = bstart + tid; i < bend; i += 256)
        atomicAdd(&cnt[ebuf[i] & 255], 1);
    // init whole padded region to sentinel (overwritten by real edges below)
    for (int i = rbeg + tid; i < rend; i += 256) ssrc[i] = n;
    __syncthreads();
    int v = cnt[tid];
    int pv = (v + 7) & ~7;        // row padded to multiple of 8
    int val = pv;
    sc[tid] = val; __syncthreads();
    for (int o = 1; o < 256; o <<= 1) {
        int t = (tid >= o) ? sc[tid - o] : 0;
        __syncthreads();
        val += t; sc[tid] = val;
        __syncthreads();
    }
    int excl = val - pv;
    int node = node0 + tid;
    if (node < n) {
        row_start[node] = rbeg + excl;
        dinv[node] = rsqrtf((float)v + 1.0f);
    }
    cur[tid] = rbeg + excl;
    if (b == NB - 1 && tid == 0) row_start[n] = rend;
    __syncthreads();
    for (int i = bstart + tid; i < bend; i += 256) {
        int e = ebuf[i];
        int pos = atomicAdd(&cur[e & 255], 1);
        ssrc[pos] = e >> 8;        // s < 2^23, sign-safe
    }
}

// ---------------- fp32 -> bf16 convert with dinv pre-scale ----------------
__global__ __launch_bounds__(256) void k_cvt(const float* __restrict__ x,
                                             const float* __restrict__ dinv,
                                             ushort* __restrict__ xb, int total) {
    int i = (blockIdx.x * 256 + threadIdx.x) * 4;
    if (i >= total) return;
    float d = dinv[i >> 7];
    float4 v = *(const float4*)(x + i);
    uint2 o;
    o.x = (uint)f2bf(v.x * d) | ((uint)f2bf(v.y * d) << 16);
    o.y = (uint)f2bf(v.z * d) | ((uint)f2bf(v.w * d) << 16);
    *(uint2*)(xb + i) = o;
}

// --- fused prep: W1->Wt (bf16 transp); Wct=(W2*Wfc)^T bf16; bc=b2*Wfc+bfc;
// --- plus zeroing of the sentinel rows of xb (128ch) and tb (64ch).
__global__ __launch_bounds__(256) void k_prep(const float* __restrict__ W1,
                                              const float* __restrict__ W2,
                                              const float* __restrict__ b2,
                                              const float* __restrict__ Wfc,
                                              const float* __restrict__ bfc,
                                              ushort* __restrict__ Wt,
                                              ushort* __restrict__ Wct,
                                              float* __restrict__ bc,
                                              ushort* __restrict__ xb,
                                              ushort* __restrict__ tb, int n) {
    const int T0 = CH * CH;
    const int T1 = T0 + CH * OC;
    const int T2 = T1 + OC;
    const int T3 = T2 + CH;
    const int T4 = T3 + OC;
    int t = blockIdx.x * 256 + threadIdx.x;
    if (t < T0) {
        int nc = t >> 7, k = t & 127;
        Wt[nc * CH + k] = f2bf(W1[k * CH + nc]);
    } else if (t < T1) {
        int u = t - T0;
        int k = u >> 6, o = u & 63;
        float acc = 0.f;
        for (int j = 0; j < CH; j++) acc += W2[k * CH + j] * Wfc[j * OC + o];
        Wct[o * CH + k] = f2bf(acc);   // [OC][CH] bf16, MFMA B-operand layout
    } else if (t < T2) {
        int o = t - T1;
        float acc = bfc[o];
        for (int j = 0; j < CH; j++) acc += b2[j] * Wfc[j * OC + o];
        bc[o] = acc;
    } else if (t < T3) {
        xb[(size_t)n * CH + (t - T2)] = 0;   // sentinel row, 128ch
    } else if (t < T4) {
        tb[(size_t)n * OC + (t - T3)] = 0;   // sentinel row, 64ch
    }
}

// ------- aggregation (128 ch): quarter-wave per edge, mask-free ------------
// out = dinv_dst * (sum_e Hs[src_e] + Hs[dst]); Hs pre-scaled by dinv.
// Rows padded to x8 with sentinel (zero) sources -> no masks, no min.
__global__ __launch_bounds__(256) void k_agg(const ushort* __restrict__ Hs,
                                             const int* __restrict__ rs,
                                             const int* __restrict__ ssrc,
                                             const float* __restrict__ dinv,
                                             ushort* __restrict__ out, int n) {
    int wid = (blockIdx.x << 2) | (threadIdx.x >> 6);
    if (wid >= n) return;
    int uw = __builtin_amdgcn_readfirstlane(wid);
    int lane = threadIdx.x & 63;
    int sub = lane >> 4;          // edge slot within group of 4
    int li = lane & 15;
    int c = li * 8;               // 8 bf16 channels = 16 B per lane
    float a0 = 0.f, a1 = 0.f, a2 = 0.f, a3 = 0.f;
    float a4 = 0.f, a5 = 0.f, a6 = 0.f, a7 = 0.f;
    if (sub == 0) {
        uint4 sv = *(const uint4*)(Hs + ((size_t)uw << 7) + c);
        a0 = bf_lo(sv.x); a1 = bf_hi(sv.x);
        a2 = bf_lo(sv.y); a3 = bf_hi(sv.y);
        a4 = bf_lo(sv.z); a5 = bf_hi(sv.z);
        a6 = bf_lo(sv.w); a7 = bf_hi(sv.w);
    }
    int e0 = rs[uw], e1 = rs[uw + 1];
    int e = e0;
    for (; e + 16 <= e1; e += 16) {
        int s0 = ssrc[e + sub];
        int s1 = ssrc[e + 4 + sub];
        int s2 = ssrc[e + 8 + sub];
        int s3 = ssrc[e + 12 + sub];
        uint4 g0 = *(const uint4*)(Hs + (s0 << 7) + c);
        uint4 g1 = *(const uint4*)(Hs + (s1 << 7) + c);
        uint4 g2 = *(const uint4*)(Hs + (s2 << 7) + c);
        uint4 g3 = *(const uint4*)(Hs + (s3 << 7) + c);
        a0 += bf_lo(g0.x); a1 += bf_hi(g0.x);
        a2 += bf_lo(g0.y); a3 += bf_hi(g0.y);
        a4 += bf_lo(g0.z); a5 += bf_hi(g0.z);
        a6 += bf_lo(g0.w); a7 += bf_hi(g0.w);
        a0 += bf_lo(g1.x); a1 += bf_hi(g1.x);
        a2 += bf_lo(g1.y); a3 += bf_hi(g1.y);
        a4 += bf_lo(g1.z); a5 += bf_hi(g1.z);
        a6 += bf_lo(g1.w); a7 += bf_hi(g1.w);
        a0 += bf_lo(g2.x); a1 += bf_hi(g2.x);
        a2 += bf_lo(g2.y); a3 += bf_hi(g2.y);
        a4 += bf_lo(g2.z); a5 += bf_hi(g2.z);
        a6 += bf_lo(g2.w); a7 += bf_hi(g2.w);
        a0 += bf_lo(g3.x); a1 += bf_hi(g3.x);
        a2 += bf_lo(g3.y); a3 += bf_hi(g3.y);
        a4 += bf_lo(g3.z); a5 += bf_hi(g3.z);
        a6 += bf_lo(g3.w); a7 += bf_hi(g3.w);
    }
    if (e < e1) {                 // exactly 8 remaining (rows padded to x8)
        int s0 = ssrc[e + sub];
        int s1 = ssrc[e + 4 + sub];
        uint4 g0 = *(const uint4*)(Hs + (s0 << 7) + c);
        uint4 g1 = *(const uint4*)(Hs + (s1 << 7) + c);
        a0 += bf_lo(g0.x); a1 += bf_hi(g0.x);
        a2 += bf_lo(g0.y); a3 += bf_hi(g0.y);
        a4 += bf_lo(g0.z); a5 += bf_hi(g0.z);
        a6 += bf_lo(g0.w); a7 += bf_hi(g0.w);
        a0 += bf_lo(g1.x); a1 += bf_hi(g1.x);
        a2 += bf_lo(g1.y); a3 += bf_hi(g1.y);
        a4 += bf_lo(g1.z); a5 += bf_hi(g1.z);
        a6 += bf_lo(g1.w); a7 += bf_hi(g1.w);
    }
    a0 += __shfl_xor(a0, 16); a0 += __shfl_xor(a0, 32);
    a1 += __shfl_xor(a1, 16); a1 += __shfl_xor(a1, 32);
    a2 += __shfl_xor(a2, 16); a2 += __shfl_xor(a2, 32);
    a3 += __shfl_xor(a3, 16); a3 += __shfl_xor(a3, 32);
    a4 += __shfl_xor(a4, 16); a4 += __shfl_xor(a4, 32);
    a5 += __shfl_xor(a5, 16); a5 += __shfl_xor(a5, 32);
    a6 += __shfl_xor(a6, 16); a6 += __shfl_xor(a6, 32);
    a7 += __shfl_xor(a7, 16); a7 += __shfl_xor(a7, 32);
    if (sub == 0) {
        float d = dinv[uw];
        uint4 o;
        o.x = (uint)f2bf(a0 * d) | ((uint)f2bf(a1 * d) << 16);
        o.y = (uint)f2bf(a2 * d) | ((uint)f2bf(a3 * d) << 16);
        o.z = (uint)f2bf(a4 * d) | ((uint)f2bf(a5 * d) << 16);
        o.w = (uint)f2bf(a6 * d) | ((uint)f2bf(a7 * d) << 16);
        *(uint4*)(out + ((size_t)uw << 7) + c) = o;
    }
}

// ------- aggregation (64 ch): eighth-wave per edge, mask-free ---------------
__global__ __launch_bounds__(256) void k_agg64(const ushort* __restrict__ Hs,
                                               const int* __restrict__ rs,
                                               const int* __restrict__ ssrc,
                                               const float* __restrict__ dinv,
                                               ushort* __restrict__ out, int n) {
    int wid = (blockIdx.x << 2) | (threadIdx.x >> 6);
    if (wid >= n) return;
    int uw = __builtin_amdgcn_readfirstlane(wid);
    int lane = threadIdx.x & 63;
    int sub = lane >> 3;          // 8 edge slots
    int li = lane & 7;
    int c = li * 8;               // 8 bf16 channels = 16 B per lane, 8 lanes/row
    float a0 = 0.f, a1 = 0.f, a2 = 0.f, a3 = 0.f;
    float a4 = 0.f, a5 = 0.f, a6 = 0.f, a7 = 0.f;
    if (sub == 0) {
        uint4 sv = *(const uint4*)(Hs + ((size_t)uw << 6) + c);
        a0 = bf_lo(sv.x); a1 = bf_hi(sv.x);
        a2 = bf_lo(sv.y); a3 = bf_hi(sv.y);
        a4 = bf_lo(sv.z); a5 = bf_hi(sv.z);
        a6 = bf_lo(sv.w); a7 = bf_hi(sv.w);
    }
    int e0 = rs[uw], e1 = rs[uw + 1];
    int e = e0;
    for (; e + 16 <= e1; e += 16) {
        int s0 = ssrc[e + sub];
        int s1 = ssrc[e + 8 + sub];
        uint4 g0 = *(const uint4*)(Hs + (s0 << 6) + c);
        uint4 g1 = *(const uint4*)(Hs + (s1 << 6) + c);
        a0 += bf_lo(g0.x); a1 += bf_hi(g0.x);
        a2 += bf_lo(g0.y); a3 += bf_hi(g0.y);
        a4 += bf_lo(g0.z); a5 += bf_hi(g0.z);
        a6 += bf_lo(g0.w); a7 += bf_hi(g0.w);
        a0 += bf_lo(g1.x); a1 += bf_hi(g1.x);
        a2 += bf_lo(g1.y); a3 += bf_hi(g1.y);
        a4 += bf_lo(g1.z); a5 += bf_hi(g1.z);
        a6 += bf_lo(g1.w); a7 += bf_hi(g1.w);
    }
    if (e < e1) {                 // exactly 8 remaining
        int s0 = ssrc[e + sub];
        uint4 g0 = *(const uint4*)(Hs + (s0 << 6) + c);
        a0 += bf_lo(g0.x); a1 += bf_hi(g0.x);
        a2 += bf_lo(g0.y); a3 += bf_hi(g0.y);
        a4 += bf_lo(g0.z); a5 += bf_hi(g0.z);
        a6 += bf_lo(g0.w); a7 += bf_hi(g0.w);
    }
    a0 += __shfl_xor(a0, 8); a0 += __shfl_xor(a0, 16); a0 += __shfl_xor(a0, 32);
    a1 += __shfl_xor(a1, 8); a1 += __shfl_xor(a1, 16); a1 += __shfl_xor(a1, 32);
    a2 += __shfl_xor(a2, 8); a2 += __shfl_xor(a2, 16); a2 += __shfl_xor(a2, 32);
    a3 += __shfl_xor(a3, 8); a3 += __shfl_xor(a3, 16); a3 += __shfl_xor(a3, 32);
    a4 += __shfl_xor(a4, 8); a4 += __shfl_xor(a4, 16); a4 += __shfl_xor(a4, 32);
    a5 += __shfl_xor(a5, 8); a5 += __shfl_xor(a5, 16); a5 += __shfl_xor(a5, 32);
    a6 += __shfl_xor(a6, 8); a6 += __shfl_xor(a6, 16); a6 += __shfl_xor(a6, 32);
    a7 += __shfl_xor(a7, 8); a7 += __shfl_xor(a7, 16); a7 += __shfl_xor(a7, 32);
    if (sub == 0) {
        float d = dinv[uw];
        uint4 o;
        o.x = (uint)f2bf(a0 * d) | ((uint)f2bf(a1 * d) << 16);
        o.y = (uint)f2bf(a2 * d) | ((uint)f2bf(a3 * d) << 16);
        o.z = (uint)f2bf(a4 * d) | ((uint)f2bf(a5 * d) << 16);
        o.w = (uint)f2bf(a6 * d) | ((uint)f2bf(a7 * d) << 16);
        *(uint4*)(out + ((size_t)uw << 6) + c) = o;
    }
}

// ---- T = (dinv*relu(Y*W1 + b1)) * Wct : two MFMA stages, LDS tile reuse ----
__global__ __launch_bounds__(256) void k_gemm_mfma(const ushort* __restrict__ Y,
                                                   const ushort* __restrict__ Wt,
                                                   const float* __restrict__ bias,
                                                   const float* __restrict__ dinv,
                                                   const ushort* __restrict__ Wct,
                                                   ushort* __restrict__ T, int n) {
    __shared__ __align__(16) ushort As[128][136];
    int tid = threadIdx.x;
    int r0 = blockIdx.x * 128;
#pragma unroll
    for (int i = 0; i < 8; i++) {
        int idx = tid + i * 256;
        int row = idx >> 4;
        int c8 = (idx & 15) * 8;
        int r = r0 + row;
        uint4 v = make_uint4(0u, 0u, 0u, 0u);
        if (r < n) v = *(const uint4*)(Y + (size_t)r * CH + c8);
        *(uint4*)&As[row][c8] = v;
    }
    __syncthreads();
    int w = tid >> 6, lane = tid & 63;
    int qm = lane & 15, quad = lane >> 4;
    floatx4 acc[2][8];
#pragma unroll
    for (int mi = 0; mi < 2; mi++)
#pragma unroll
        for (int nt = 0; nt < 8; nt++) acc[mi][nt] = (floatx4){0.f, 0.f, 0.f, 0.f};
#pragma unroll
    for (int ks = 0; ks < 4; ks++) {
        int k0 = ks * 32 + quad * 8;
        short8 va0 = *(const short8*)&As[w * 32 + qm][k0];
        short8 va1 = *(const short8*)&As[w * 32 + 16 + qm][k0];
#pragma unroll
        for (int nt = 0; nt < 8; nt++) {
            short8 b = *(const short8*)(Wt + (nt * 16 + qm) * CH + k0);
            acc[0][nt] = __builtin_amdgcn_mfma_f32_16x16x32_bf16(va0, b, acc[0][nt], 0, 0, 0);
            acc[1][nt] = __builtin_amdgcn_mfma_f32_16x16x32_bf16(va1, b, acc[1][nt], 0, 0, 0);
        }
    }
    // epilogue stage 1: hs = dinv*relu(acc+bias), write bf16 back to own rows
#pragma unroll
    for (int mi = 0; mi < 2; mi++) {
#pragma unroll
        for (int reg = 0; reg < 4; reg++) {
            int lrow = w * 32 + mi * 16 + quad * 4 + reg;
            int r = r0 + lrow;
            float d = (r < n) ? dinv[r] : 0.f;   // pad rows -> exact 0
#pragma unroll
            for (int nt = 0; nt < 8; nt++) {
                int cidx = nt * 16 + qm;
                float val = fmaxf(acc[mi][nt][reg] + bias[cidx], 0.f) * d;
                As[lrow][cidx] = f2bf(val);
            }
        }
    }
    __syncthreads();
    // stage 2: T tile = hs(128x128) * Wct(64x128)^T
    floatx4 acc2[2][4];
#pragma unroll
    for (int mi = 0; mi < 2; mi++)
#pragma unroll
        for (int nt = 0; nt < 4; nt++) acc2[mi][nt] = (floatx4){0.f, 0.f, 0.f, 0.f};
#pragma unroll
    for (int ks = 0; ks < 4; ks++) {
        int k0 = ks * 32 + quad * 8;
        short8 va0 = *(const short8*)&As[w * 32 + qm][k0];
        short8 va1 = *(const short8*)&As[w * 32 + 16 + qm][k0];
#pragma unroll
        for (int nt = 0; nt < 4; nt++) {
            short8 b = *(const short8*)(Wct + (nt * 16 + qm) * CH + k0);
            acc2[0][nt] = __builtin_amdgcn_mfma_f32_16x16x32_bf16(va0, b, acc2[0][nt], 0, 0, 0);
            acc2[1][nt] = __builtin_amdgcn_mfma_f32_16x16x32_bf16(va1, b, acc2[1][nt], 0, 0, 0);
        }
    }
#pragma unroll
    for (int mi = 0; mi < 2; mi++) {
#pragma unroll
        for (int reg = 0; reg < 4; reg++) {
            int r = r0 + w * 32 + mi * 16 + quad * 4 + reg;
            if (r >= n) continue;
#pragma unroll
            for (int nt = 0; nt < 4; nt++)
                T[(size_t)r * OC + nt * 16 + qm] = f2bf(acc2[mi][nt][reg]);
        }
    }
}

// ------ pool (64 ch): node-range sweep, per-graph flush with fp32 atomics ----
__global__ __launch_bounds__(256) void k_pool64(const ushort* __restrict__ Z,
                                                const int* __restrict__ batch,
                                                float* __restrict__ Qs,
                                                float* __restrict__ cnt,
                                                int n, int npb) {
    int lo = blockIdx.x * npb;
    if (lo >= n) return;
    int hi = min(n, lo + npb);
    int w = threadIdx.x >> 6, lane = threadIdx.x & 63;
    float a0 = 0.f;
    int curg = -1, rc = 0;
    for (int i = lo + w; i < hi; i += 4) {
        int g = batch[i];
        if (g != curg) {
            if (rc > 0) {
                atomicAdd(&Qs[curg * OC + lane], a0);
                if (lane == 0) atomicAdd(&cnt[curg], (float)rc);
            }
            curg = g; a0 = 0.f; rc = 0;
        }
        a0 += __uint_as_float(((uint)Z[(size_t)i * OC + lane]) << 16);
        rc++;
    }
    if (rc > 0) {
        atomicAdd(&Qs[curg * OC + lane], a0);
        if (lane == 0) atomicAdd(&cnt[curg], (float)rc);
    }
}

// ---------------- out = Qs/cnt + bc ----------------
__global__ __launch_bounds__(256) void k_out(const float* __restrict__ Qs,
                                             const float* __restrict__ cnt,
                                             const float* __restrict__ bc,
                                             float* __restrict__ out) {
    int t = blockIdx.x * 256 + threadIdx.x;
    int g = t >> 6, o = t & 63;
    float invc = 1.f / fmaxf(cnt[g], 1.f);
    out[t] = Qs[t] * invc + bc[o];
}

extern "C" void kernel_launch(void* const* d_in, const int* in_sizes, int n_in,
                              void* d_out, int out_size, void* d_ws, size_t ws_size,
                              hipStream_t stream) {
    const float* x   = (const float*)d_in[0];
    const float* W1  = (const float*)d_in[1];
    const float* b1  = (const float*)d_in[2];
    const float* W2  = (const float*)d_in[3];
    const float* b2  = (const float*)d_in[4];
    const float* Wfc = (const float*)d_in[5];
    const float* bfc = (const float*)d_in[6];
    const int* edges = (const int*)d_in[7];
    const int* batch = (const int*)d_in[8];

    const int n = in_sizes[8];        // 100000
    const int E = in_sizes[7] / 2;    // 1600000
    const int* esrc = edges;
    const int* edst = edges + E;

    const int NB = (n + 255) >> 8;            // 391 coarse buckets
    const int T = NB * NBLK;
    const int chunk = (E + NBLK - 1) / NBLK;

    char* p = (char*)d_ws;
    auto carve = [&](size_t bytes) {
        void* r = (void*)p;
        p += (bytes + 255) & ~(size_t)255;
        return r;
    };
    int*    bhT       = (int*)carve((size_t)T * 4);
    int*    off       = (int*)carve((size_t)T * 4);
    int*    bsums     = (int*)carve(512);
    int*    ebuf      = (int*)carve((size_t)E * 4);
    int*    row_start = (int*)carve((size_t)(n + 1) * 4);
    float*  dinv      = (float*)carve((size_t)n * 4);
    int*    ssrc      = (int*)carve(((size_t)E + (size_t)NB * PADSLACK + 256) * 4);
    ushort* xb        = (ushort*)carve((size_t)(n + 1) * CH * 2);  // +sentinel row
    ushort* yb        = (ushort*)carve((size_t)n * CH * 2);
    ushort* tb        = (ushort*)carve((size_t)(n + 1) * OC * 2);  // +sentinel row
    ushort* Wt        = (ushort*)carve((size_t)CH * CH * 2);
    float*  q         = (float*)carve((size_t)NG * OC * 4);
    float*  cnt       = (float*)carve((size_t)NG * 4);
    ushort* Wct       = (ushort*)carve((size_t)OC * CH * 2);
    float*  bc        = (float*)carve((size_t)OC * 4);

    int nScanBlocks = (T + 1023) / 1024;
    int npb = (n + POOLB - 1) / POOLB;

    hipMemsetAsync(q, 0, (size_t)(NG * OC + NG) * 4, stream);

    // CSR build (atomic-free global ordering, rows padded to x8 w/ sentinel)
    k_hist<<<NBLK, 256, 0, stream>>>(edst, bhT, E, NB, chunk);
    k_scan1<<<nScanBlocks, 256, 0, stream>>>(bhT, off, bsums, T);
    k_scan2<<<1, 128, 0, stream>>>(bsums, nScanBlocks);
    k_part<<<NBLK, 256, 0, stream>>>(esrc, edst, off, bsums, ebuf, E, NB, chunk);
    k_csr<<<NB, 256, 0, stream>>>(ebuf, off, bsums, row_start, dinv, ssrc, n, NB, E);

    // features + weight prep (k_prep also zeroes sentinel rows of xb/tb)
    k_cvt<<<(n * CH / 4 + 255) / 256, 256, 0, stream>>>(x, dinv, xb, n * CH);
    k_prep<<<(CH * CH + CH * OC + OC + CH + OC + 255) / 256, 256, 0, stream>>>(
        W1, W2, b2, Wfc, bfc, Wt, Wct, bc, xb, tb, n);
    // y = dinv*(sum Xs + self)   (xb -> yb, 128 ch)
    k_agg<<<(n + 3) / 4, 256, 0, stream>>>(xb, row_start, ssrc, dinv, yb, n);
    // t = (dinv*relu(y*W1 + b1)) * Wct   (yb -> tb, 64 ch)
    k_gemm_mfma<<<(n + 127) / 128, 256, 0, stream>>>(yb, Wt, b1, dinv, Wct, tb, n);
    // z = dinv*(sum T + self)   (tb -> xb-as-64ch)
    k_agg64<<<(n + 3) / 4, 256, 0, stream>>>(tb, row_start, ssrc, dinv, xb, n);
    // q = sum-pool(z), cnt via atomics
    k_pool64<<<POOLB, 256, 0, stream>>>(xb, batch, q, cnt, n, npb);
    // out = q/cnt + bc
    k_out<<<(NG * OC + 255) / 256, 256, 0, stream>>>(q, cnt, bc, (float*)d_out);
}

// Round 3
// 318.235 us; speedup vs baseline: 1.6832x; 1.6832x over previous
//
#include <hip/hip_runtime.h>
#include <stdint.h>

#define NN 100000
#define NE 1600000
#define CH 128
#define OC 64
#define NG 512
#define NBLK 256      // partition blocks
#define NBMAX 4096    // max coarse buckets (nodes/256)
#define POOLB 400     // pool blocks
#define PADSLACK 1792 // per-bucket ssrc padding slack: 256 nodes * 7

typedef unsigned int uint;
typedef unsigned short ushort;
typedef __attribute__((ext_vector_type(8))) short short8;
typedef __attribute__((ext_vector_type(4))) float floatx4;

__device__ __forceinline__ ushort f2bf(float f) {
    uint u = __float_as_uint(f);
    uint r = u + 0x7fffu + ((u >> 16) & 1u);  // round-to-nearest-even
    return (ushort)(r >> 16);
}
__device__ __forceinline__ float bf_lo(uint g) { return __uint_as_float(g << 16); }
__device__ __forceinline__ float bf_hi(uint g) { return __uint_as_float(g & 0xffff0000u); }

// ---------------- bucket histogram, written bucket-major ----------------
__global__ __launch_bounds__(256) void k_hist(const int* __restrict__ dst,
                                              int* __restrict__ bhT,
                                              int E, int NB, int chunk) {
    __shared__ int h[NBMAX];
    int blk = blockIdx.x, tid = threadIdx.x;
    for (int j = tid; j < NB; j += 256) h[j] = 0;
    __syncthreads();
    int lo = blk * chunk, hi = min(E, lo + chunk);
    for (int i = lo + tid; i < hi; i += 256) atomicAdd(&h[dst[i] >> 8], 1);
    __syncthreads();
    for (int j = tid; j < NB; j += 256) bhT[j * NBLK + blk] = h[j];
}

// ---------------- prefix scan (2-phase; block offsets folded by consumers) ---
__global__ __launch_bounds__(256) void k_scan1(const int* __restrict__ in,
                                               int* __restrict__ excl,
                                               int* __restrict__ bsums, int T) {
    __shared__ int sd[256];
    int tid = threadIdx.x;
    int base = blockIdx.x * 1024 + tid * 4;
    int v[4];
#pragma unroll
    for (int i = 0; i < 4; i++) v[i] = (base + i < T) ? in[base + i] : 0;
    int tsum = v[0] + v[1] + v[2] + v[3];
    int val = tsum;
    sd[tid] = val; __syncthreads();
    for (int off = 1; off < 256; off <<= 1) {
        int t = (tid >= off) ? sd[tid - off] : 0;
        __syncthreads();
        val += t; sd[tid] = val;
        __syncthreads();
    }
    int run = val - tsum;
#pragma unroll
    for (int i = 0; i < 4; i++) {
        if (base + i < T) excl[base + i] = run;
        run += v[i];
    }
    if (tid == 255) bsums[blockIdx.x] = val;
}

__global__ __launch_bounds__(128) void k_scan2(int* __restrict__ bs, int nb) {
    __shared__ int sd[128];
    int tid = threadIdx.x;
    int v = (tid < nb) ? bs[tid] : 0;
    int val = v;
    sd[tid] = val; __syncthreads();
    for (int off = 1; off < 128; off <<= 1) {
        int t = (tid >= off) ? sd[tid - off] : 0;
        __syncthreads();
        val += t; sd[tid] = val;
        __syncthreads();
    }
    if (tid < nb) bs[tid] = val - v;
}

// ------- partition: packed (src<<8)|(dst&255) into per-(bucket,block) segs ----
__global__ __launch_bounds__(256) void k_part(const int* __restrict__ src,
                                              const int* __restrict__ dst,
                                              const int* __restrict__ off,
                                              const int* __restrict__ boff,
                                              int* __restrict__ ebuf,
                                              int E, int NB, int chunk) {
    __shared__ int cur[NBMAX];
    int blk = blockIdx.x, tid = threadIdx.x;
    for (int j = tid; j < NB; j += 256) {
        int idx = j * NBLK + blk;
        cur[j] = off[idx] + boff[idx >> 10];
    }
    __syncthreads();
    int lo = blk * chunk, hi = min(E, lo + chunk);
    for (int i = lo + tid; i < hi; i += 256) {
        int s = src[i], d = dst[i];
        int pos = atomicAdd(&cur[d >> 8], 1);
        ebuf[pos] = (s << 8) | (d & 255);
    }
}

// ------- CSR finalize per bucket: deg, dinv, (start,end), padded scatter -----
// Rows padded to multiple of 8; pad slots filled with sentinel node index n
// (whose feature row is all zeros). Row extent stored EXPLICITLY as int2 so
// bucket slack gaps are never scanned (round-2 straggler bug fix).
__global__ __launch_bounds__(256) void k_csr(const int* __restrict__ ebuf,
                                             const int* __restrict__ off,
                                             const int* __restrict__ boff,
                                             int2* __restrict__ rowse,
                                             float* __restrict__ dinv,
                                             int* __restrict__ ssrc,
                                             int n, int NB, int E) {
    __shared__ int cnt[256], sc[256], cur[256];
    int b = blockIdx.x, tid = threadIdx.x;
    int node0 = b << 8;
    int i0 = b * NBLK;
    int bstart = off[i0] + boff[i0 >> 10];
    int bend = E;
    if (b + 1 < NB) {
        int i1 = (b + 1) * NBLK;
        bend = off[i1] + boff[i1 >> 10];
    }
    // padded ssrc region for this bucket
    int rbeg = bstart + b * PADSLACK;
    int rend = bend + (b + 1) * PADSLACK;
    cnt[tid] = 0;
    __syncthreads();
    for (int i = bstart + tid; i < bend; i += 256)
        atomicAdd(&cnt[ebuf[i] & 255], 1);
    // init whole padded region to sentinel (real edges overwrite below)
    for (int i = rbeg + tid; i < rend; i += 256) ssrc[i] = n;
    __syncthreads();
    int v = cnt[tid];
    int pv = (v + 7) & ~7;        // row padded to multiple of 8
    int val = pv;
    sc[tid] = val; __syncthreads();
    for (int o = 1; o < 256; o <<= 1) {
        int t = (tid >= o) ? sc[tid - o] : 0;
        __syncthreads();
        val += t; sc[tid] = val;
        __syncthreads();
    }
    int excl = val - pv;
    int node = node0 + tid;
    if (node < n) {
        rowse[node] = make_int2(rbeg + excl, rbeg + excl + pv);
        dinv[node] = rsqrtf((float)v + 1.0f);
    }
    cur[tid] = rbeg + excl;
    __syncthreads();
    for (int i = bstart + tid; i < bend; i += 256) {
        int e = ebuf[i];
        int pos = atomicAdd(&cur[e & 255], 1);
        ssrc[pos] = e >> 8;        // s < 2^23, sign-safe
    }
}

// ---------------- fp32 -> bf16 convert with dinv pre-scale ----------------
__global__ __launch_bounds__(256) void k_cvt(const float* __restrict__ x,
                                             const float* __restrict__ dinv,
                                             ushort* __restrict__ xb, int total) {
    int i = (blockIdx.x * 256 + threadIdx.x) * 4;
    if (i >= total) return;
    float d = dinv[i >> 7];
    float4 v = *(const float4*)(x + i);
    uint2 o;
    o.x = (uint)f2bf(v.x * d) | ((uint)f2bf(v.y * d) << 16);
    o.y = (uint)f2bf(v.z * d) | ((uint)f2bf(v.w * d) << 16);
    *(uint2*)(xb + i) = o;
}

// --- fused prep: W1->Wt (bf16 transp); Wct=(W2*Wfc)^T bf16; bc=b2*Wfc+bfc;
// --- plus zeroing of the sentinel rows of xb (128ch) and tb (64ch).
__global__ __launch_bounds__(256) void k_prep(const float* __restrict__ W1,
                                              const float* __restrict__ W2,
                                              const float* __restrict__ b2,
                                              const float* __restrict__ Wfc,
                                              const float* __restrict__ bfc,
                                              ushort* __restrict__ Wt,
                                              ushort* __restrict__ Wct,
                                              float* __restrict__ bc,
                                              ushort* __restrict__ xb,
                                              ushort* __restrict__ tb, int n) {
    const int T0 = CH * CH;
    const int T1 = T0 + CH * OC;
    const int T2 = T1 + OC;
    const int T3 = T2 + CH;
    const int T4 = T3 + OC;
    int t = blockIdx.x * 256 + threadIdx.x;
    if (t < T0) {
        int nc = t >> 7, k = t & 127;
        Wt[nc * CH + k] = f2bf(W1[k * CH + nc]);
    } else if (t < T1) {
        int u = t - T0;
        int k = u >> 6, o = u & 63;
        float acc = 0.f;
        for (int j = 0; j < CH; j++) acc += W2[k * CH + j] * Wfc[j * OC + o];
        Wct[o * CH + k] = f2bf(acc);   // [OC][CH] bf16, MFMA B-operand layout
    } else if (t < T2) {
        int o = t - T1;
        float acc = bfc[o];
        for (int j = 0; j < CH; j++) acc += b2[j] * Wfc[j * OC + o];
        bc[o] = acc;
    } else if (t < T3) {
        xb[(size_t)n * CH + (t - T2)] = 0;   // sentinel row, 128ch
    } else if (t < T4) {
        tb[(size_t)n * OC + (t - T3)] = 0;   // sentinel row, 64ch
    }
}

// ------- aggregation (128 ch): quarter-wave per edge, mask-free ------------
// out = dinv_dst * (sum_e Hs[src_e] + Hs[dst]); Hs pre-scaled by dinv.
// Rows padded to x8 with sentinel (zero) sources -> no masks, no min.
__global__ __launch_bounds__(256) void k_agg(const ushort* __restrict__ Hs,
                                             const int2* __restrict__ rowse,
                                             const int* __restrict__ ssrc,
                                             const float* __restrict__ dinv,
                                             ushort* __restrict__ out, int n) {
    int wid = (blockIdx.x << 2) | (threadIdx.x >> 6);
    if (wid >= n) return;
    int uw = __builtin_amdgcn_readfirstlane(wid);
    int lane = threadIdx.x & 63;
    int sub = lane >> 4;          // edge slot within group of 4
    int li = lane & 15;
    int c = li * 8;               // 8 bf16 channels = 16 B per lane
    float a0 = 0.f, a1 = 0.f, a2 = 0.f, a3 = 0.f;
    float a4 = 0.f, a5 = 0.f, a6 = 0.f, a7 = 0.f;
    if (sub == 0) {
        uint4 sv = *(const uint4*)(Hs + ((size_t)uw << 7) + c);
        a0 = bf_lo(sv.x); a1 = bf_hi(sv.x);
        a2 = bf_lo(sv.y); a3 = bf_hi(sv.y);
        a4 = bf_lo(sv.z); a5 = bf_hi(sv.z);
        a6 = bf_lo(sv.w); a7 = bf_hi(sv.w);
    }
    int2 se = rowse[uw];
    int e = se.x, e1 = se.y;
    for (; e + 16 <= e1; e += 16) {
        int s0 = ssrc[e + sub];
        int s1 = ssrc[e + 4 + sub];
        int s2 = ssrc[e + 8 + sub];
        int s3 = ssrc[e + 12 + sub];
        uint4 g0 = *(const uint4*)(Hs + (s0 << 7) + c);
        uint4 g1 = *(const uint4*)(Hs + (s1 << 7) + c);
        uint4 g2 = *(const uint4*)(Hs + (s2 << 7) + c);
        uint4 g3 = *(const uint4*)(Hs + (s3 << 7) + c);
        a0 += bf_lo(g0.x); a1 += bf_hi(g0.x);
        a2 += bf_lo(g0.y); a3 += bf_hi(g0.y);
        a4 += bf_lo(g0.z); a5 += bf_hi(g0.z);
        a6 += bf_lo(g0.w); a7 += bf_hi(g0.w);
        a0 += bf_lo(g1.x); a1 += bf_hi(g1.x);
        a2 += bf_lo(g1.y); a3 += bf_hi(g1.y);
        a4 += bf_lo(g1.z); a5 += bf_hi(g1.z);
        a6 += bf_lo(g1.w); a7 += bf_hi(g1.w);
        a0 += bf_lo(g2.x); a1 += bf_hi(g2.x);
        a2 += bf_lo(g2.y); a3 += bf_hi(g2.y);
        a4 += bf_lo(g2.z); a5 += bf_hi(g2.z);
        a6 += bf_lo(g2.w); a7 += bf_hi(g2.w);
        a0 += bf_lo(g3.x); a1 += bf_hi(g3.x);
        a2 += bf_lo(g3.y); a3 += bf_hi(g3.y);
        a4 += bf_lo(g3.z); a5 += bf_hi(g3.z);
        a6 += bf_lo(g3.w); a7 += bf_hi(g3.w);
    }
    if (e < e1) {                 // exactly 8 remaining (rows padded to x8)
        int s0 = ssrc[e + sub];
        int s1 = ssrc[e + 4 + sub];
        uint4 g0 = *(const uint4*)(Hs + (s0 << 7) + c);
        uint4 g1 = *(const uint4*)(Hs + (s1 << 7) + c);
        a0 += bf_lo(g0.x); a1 += bf_hi(g0.x);
        a2 += bf_lo(g0.y); a3 += bf_hi(g0.y);
        a4 += bf_lo(g0.z); a5 += bf_hi(g0.z);
        a6 += bf_lo(g0.w); a7 += bf_hi(g0.w);
        a0 += bf_lo(g1.x); a1 += bf_hi(g1.x);
        a2 += bf_lo(g1.y); a3 += bf_hi(g1.y);
        a4 += bf_lo(g1.z); a5 += bf_hi(g1.z);
        a6 += bf_lo(g1.w); a7 += bf_hi(g1.w);
    }
    a0 += __shfl_xor(a0, 16); a0 += __shfl_xor(a0, 32);
    a1 += __shfl_xor(a1, 16); a1 += __shfl_xor(a1, 32);
    a2 += __shfl_xor(a2, 16); a2 += __shfl_xor(a2, 32);
    a3 += __shfl_xor(a3, 16); a3 += __shfl_xor(a3, 32);
    a4 += __shfl_xor(a4, 16); a4 += __shfl_xor(a4, 32);
    a5 += __shfl_xor(a5, 16); a5 += __shfl_xor(a5, 32);
    a6 += __shfl_xor(a6, 16); a6 += __shfl_xor(a6, 32);
    a7 += __shfl_xor(a7, 16); a7 += __shfl_xor(a7, 32);
    if (sub == 0) {
        float d = dinv[uw];
        uint4 o;
        o.x = (uint)f2bf(a0 * d) | ((uint)f2bf(a1 * d) << 16);
        o.y = (uint)f2bf(a2 * d) | ((uint)f2bf(a3 * d) << 16);
        o.z = (uint)f2bf(a4 * d) | ((uint)f2bf(a5 * d) << 16);
        o.w = (uint)f2bf(a6 * d) | ((uint)f2bf(a7 * d) << 16);
        *(uint4*)(out + ((size_t)uw << 7) + c) = o;
    }
}

// ------- aggregation (64 ch): eighth-wave per edge, mask-free ---------------
__global__ __launch_bounds__(256) void k_agg64(const ushort* __restrict__ Hs,
                                               const int2* __restrict__ rowse,
                                               const int* __restrict__ ssrc,
                                               const float* __restrict__ dinv,
                                               ushort* __restrict__ out, int n) {
    int wid = (blockIdx.x << 2) | (threadIdx.x >> 6);
    if (wid >= n) return;
    int uw = __builtin_amdgcn_readfirstlane(wid);
    int lane = threadIdx.x & 63;
    int sub = lane >> 3;          // 8 edge slots
    int li = lane & 7;
    int c = li * 8;               // 8 bf16 channels = 16 B per lane, 8 lanes/row
    float a0 = 0.f, a1 = 0.f, a2 = 0.f, a3 = 0.f;
    float a4 = 0.f, a5 = 0.f, a6 = 0.f, a7 = 0.f;
    if (sub == 0) {
        uint4 sv = *(const uint4*)(Hs + ((size_t)uw << 6) + c);
        a0 = bf_lo(sv.x); a1 = bf_hi(sv.x);
        a2 = bf_lo(sv.y); a3 = bf_hi(sv.y);
        a4 = bf_lo(sv.z); a5 = bf_hi(sv.z);
        a6 = bf_lo(sv.w); a7 = bf_hi(sv.w);
    }
    int2 se = rowse[uw];
    int e = se.x, e1 = se.y;
    for (; e + 16 <= e1; e += 16) {
        int s0 = ssrc[e + sub];
        int s1 = ssrc[e + 8 + sub];
        uint4 g0 = *(const uint4*)(Hs + (s0 << 6) + c);
        uint4 g1 = *(const uint4*)(Hs + (s1 << 6) + c);
        a0 += bf_lo(g0.x); a1 += bf_hi(g0.x);
        a2 += bf_lo(g0.y); a3 += bf_hi(g0.y);
        a4 += bf_lo(g0.z); a5 += bf_hi(g0.z);
        a6 += bf_lo(g0.w); a7 += bf_hi(g0.w);
        a0 += bf_lo(g1.x); a1 += bf_hi(g1.x);
        a2 += bf_lo(g1.y); a3 += bf_hi(g1.y);
        a4 += bf_lo(g1.z); a5 += bf_hi(g1.z);
        a6 += bf_lo(g1.w); a7 += bf_hi(g1.w);
    }
    if (e < e1) {                 // exactly 8 remaining
        int s0 = ssrc[e + sub];
        uint4 g0 = *(const uint4*)(Hs + (s0 << 6) + c);
        a0 += bf_lo(g0.x); a1 += bf_hi(g0.x);
        a2 += bf_lo(g0.y); a3 += bf_hi(g0.y);
        a4 += bf_lo(g0.z); a5 += bf_hi(g0.z);
        a6 += bf_lo(g0.w); a7 += bf_hi(g0.w);
    }
    a0 += __shfl_xor(a0, 8); a0 += __shfl_xor(a0, 16); a0 += __shfl_xor(a0, 32);
    a1 += __shfl_xor(a1, 8); a1 += __shfl_xor(a1, 16); a1 += __shfl_xor(a1, 32);
    a2 += __shfl_xor(a2, 8); a2 += __shfl_xor(a2, 16); a2 += __shfl_xor(a2, 32);
    a3 += __shfl_xor(a3, 8); a3 += __shfl_xor(a3, 16); a3 += __shfl_xor(a3, 32);
    a4 += __shfl_xor(a4, 8); a4 += __shfl_xor(a4, 16); a4 += __shfl_xor(a4, 32);
    a5 += __shfl_xor(a5, 8); a5 += __shfl_xor(a5, 16); a5 += __shfl_xor(a5, 32);
    a6 += __shfl_xor(a6, 8); a6 += __shfl_xor(a6, 16); a6 += __shfl_xor(a6, 32);
    a7 += __shfl_xor(a7, 8); a7 += __shfl_xor(a7, 16); a7 += __shfl_xor(a7, 32);
    if (sub == 0) {
        float d = dinv[uw];
        uint4 o;
        o.x = (uint)f2bf(a0 * d) | ((uint)f2bf(a1 * d) << 16);
        o.y = (uint)f2bf(a2 * d) | ((uint)f2bf(a3 * d) << 16);
        o.z = (uint)f2bf(a4 * d) | ((uint)f2bf(a5 * d) << 16);
        o.w = (uint)f2bf(a6 * d) | ((uint)f2bf(a7 * d) << 16);
        *(uint4*)(out + ((size_t)uw << 6) + c) = o;
    }
}

// ---- T = (dinv*relu(Y*W1 + b1)) * Wct : two MFMA stages, LDS tile reuse ----
__global__ __launch_bounds__(256) void k_gemm_mfma(const ushort* __restrict__ Y,
                                                   const ushort* __restrict__ Wt,
                                                   const float* __restrict__ bias,
                                                   const float* __restrict__ dinv,
                                                   const ushort* __restrict__ Wct,
                                                   ushort* __restrict__ T, int n) {
    __shared__ __align__(16) ushort As[128][136];
    int tid = threadIdx.x;
    int r0 = blockIdx.x * 128;
#pragma unroll
    for (int i = 0; i < 8; i++) {
        int idx = tid + i * 256;
        int row = idx >> 4;
        int c8 = (idx & 15) * 8;
        int r = r0 + row;
        uint4 v = make_uint4(0u, 0u, 0u, 0u);
        if (r < n) v = *(const uint4*)(Y + (size_t)r * CH + c8);
        *(uint4*)&As[row][c8] = v;
    }
    __syncthreads();
    int w = tid >> 6, lane = tid & 63;
    int qm = lane & 15, quad = lane >> 4;
    floatx4 acc[2][8];
#pragma unroll
    for (int mi = 0; mi < 2; mi++)
#pragma unroll
        for (int nt = 0; nt < 8; nt++) acc[mi][nt] = (floatx4){0.f, 0.f, 0.f, 0.f};
#pragma unroll
    for (int ks = 0; ks < 4; ks++) {
        int k0 = ks * 32 + quad * 8;
        short8 va0 = *(const short8*)&As[w * 32 + qm][k0];
        short8 va1 = *(const short8*)&As[w * 32 + 16 + qm][k0];
#pragma unroll
        for (int nt = 0; nt < 8; nt++) {
            short8 b = *(const short8*)(Wt + (nt * 16 + qm) * CH + k0);
            acc[0][nt] = __builtin_amdgcn_mfma_f32_16x16x32_bf16(va0, b, acc[0][nt], 0, 0, 0);
            acc[1][nt] = __builtin_amdgcn_mfma_f32_16x16x32_bf16(va1, b, acc[1][nt], 0, 0, 0);
        }
    }
    // epilogue stage 1: hs = dinv*relu(acc+bias), write bf16 back to own rows
#pragma unroll
    for (int mi = 0; mi < 2; mi++) {
#pragma unroll
        for (int reg = 0; reg < 4; reg++) {
            int lrow = w * 32 + mi * 16 + quad * 4 + reg;
            int r = r0 + lrow;
            float d = (r < n) ? dinv[r] : 0.f;   // pad rows -> exact 0
#pragma unroll
            for (int nt = 0; nt < 8; nt++) {
                int cidx = nt * 16 + qm;
                float val = fmaxf(acc[mi][nt][reg] + bias[cidx], 0.f) * d;
                As[lrow][cidx] = f2bf(val);
            }
        }
    }
    __syncthreads();
    // stage 2: T tile = hs(128x128) * Wct(64x128)^T
    floatx4 acc2[2][4];
#pragma unroll
    for (int mi = 0; mi < 2; mi++)
#pragma unroll
        for (int nt = 0; nt < 4; nt++) acc2[mi][nt] = (floatx4){0.f, 0.f, 0.f, 0.f};
#pragma unroll
    for (int ks = 0; ks < 4; ks++) {
        int k0 = ks * 32 + quad * 8;
        short8 va0 = *(const short8*)&As[w * 32 + qm][k0];
        short8 va1 = *(const short8*)&As[w * 32 + 16 + qm][k0];
#pragma unroll
        for (int nt = 0; nt < 4; nt++) {
            short8 b = *(const short8*)(Wct + (nt * 16 + qm) * CH + k0);
            acc2[0][nt] = __builtin_amdgcn_mfma_f32_16x16x32_bf16(va0, b, acc2[0][nt], 0, 0, 0);
            acc2[1][nt] = __builtin_amdgcn_mfma_f32_16x16x32_bf16(va1, b, acc2[1][nt], 0, 0, 0);
        }
    }
#pragma unroll
    for (int mi = 0; mi < 2; mi++) {
#pragma unroll
        for (int reg = 0; reg < 4; reg++) {
            int r = r0 + w * 32 + mi * 16 + quad * 4 + reg;
            if (r >= n) continue;
#pragma unroll
            for (int nt = 0; nt < 4; nt++)
                T[(size_t)r * OC + nt * 16 + qm] = f2bf(acc2[mi][nt][reg]);
        }
    }
}

// ------ pool (64 ch): node-range sweep, per-graph flush with fp32 atomics ----
__global__ __launch_bounds__(256) void k_pool64(const ushort* __restrict__ Z,
                                                const int* __restrict__ batch,
                                                float* __restrict__ Qs,
                                                float* __restrict__ cnt,
                                                int n, int npb) {
    int lo = blockIdx.x * npb;
    if (lo >= n) return;
    int hi = min(n, lo + npb);
    int w = threadIdx.x >> 6, lane = threadIdx.x & 63;
    float a0 = 0.f;
    int curg = -1, rc = 0;
    for (int i = lo + w; i < hi; i += 4) {
        int g = batch[i];
        if (g != curg) {
            if (rc > 0) {
                atomicAdd(&Qs[curg * OC + lane], a0);
                if (lane == 0) atomicAdd(&cnt[curg], (float)rc);
            }
            curg = g; a0 = 0.f; rc = 0;
        }
        a0 += __uint_as_float(((uint)Z[(size_t)i * OC + lane]) << 16);
        rc++;
    }
    if (rc > 0) {
        atomicAdd(&Qs[curg * OC + lane], a0);
        if (lane == 0) atomicAdd(&cnt[curg], (float)rc);
    }
}

// ---------------- out = Qs/cnt + bc ----------------
__global__ __launch_bounds__(256) void k_out(const float* __restrict__ Qs,
                                             const float* __restrict__ cnt,
                                             const float* __restrict__ bc,
                                             float* __restrict__ out) {
    int t = blockIdx.x * 256 + threadIdx.x;
    int g = t >> 6, o = t & 63;
    float invc = 1.f / fmaxf(cnt[g], 1.f);
    out[t] = Qs[t] * invc + bc[o];
}

extern "C" void kernel_launch(void* const* d_in, const int* in_sizes, int n_in,
                              void* d_out, int out_size, void* d_ws, size_t ws_size,
                              hipStream_t stream) {
    const float* x   = (const float*)d_in[0];
    const float* W1  = (const float*)d_in[1];
    const float* b1  = (const float*)d_in[2];
    const float* W2  = (const float*)d_in[3];
    const float* b2  = (const float*)d_in[4];
    const float* Wfc = (const float*)d_in[5];
    const float* bfc = (const float*)d_in[6];
    const int* edges = (const int*)d_in[7];
    const int* batch = (const int*)d_in[8];

    const int n = in_sizes[8];        // 100000
    const int E = in_sizes[7] / 2;    // 1600000
    const int* esrc = edges;
    const int* edst = edges + E;

    const int NB = (n + 255) >> 8;            // 391 coarse buckets
    const int T = NB * NBLK;
    const int chunk = (E + NBLK - 1) / NBLK;

    char* p = (char*)d_ws;
    auto carve = [&](size_t bytes) {
        void* r = (void*)p;
        p += (bytes + 255) & ~(size_t)255;
        return r;
    };
    int*    bhT       = (int*)carve((size_t)T * 4);
    int*    off       = (int*)carve((size_t)T * 4);
    int*    bsums     = (int*)carve(512);
    int*    ebuf      = (int*)carve((size_t)E * 4);
    int2*   rowse     = (int2*)carve((size_t)n * 8);
    float*  dinv      = (float*)carve((size_t)n * 4);
    int*    ssrc      = (int*)carve(((size_t)E + (size_t)NB * PADSLACK + 256) * 4);
    ushort* xb        = (ushort*)carve((size_t)(n + 1) * CH * 2);  // +sentinel row
    ushort* yb        = (ushort*)carve((size_t)n * CH * 2);
    ushort* tb        = (ushort*)carve((size_t)(n + 1) * OC * 2);  // +sentinel row
    ushort* Wt        = (ushort*)carve((size_t)CH * CH * 2);
    float*  q         = (float*)carve((size_t)NG * OC * 4);
    float*  cnt       = (float*)carve((size_t)NG * 4);
    ushort* Wct       = (ushort*)carve((size_t)OC * CH * 2);
    float*  bc        = (float*)carve((size_t)OC * 4);

    int nScanBlocks = (T + 1023) / 1024;
    int npb = (n + POOLB - 1) / POOLB;

    hipMemsetAsync(q, 0, (size_t)(NG * OC + NG) * 4, stream);

    // CSR build (atomic-free global ordering, rows padded to x8 w/ sentinel)
    k_hist<<<NBLK, 256, 0, stream>>>(edst, bhT, E, NB, chunk);
    k_scan1<<<nScanBlocks, 256, 0, stream>>>(bhT, off, bsums, T);
    k_scan2<<<1, 128, 0, stream>>>(bsums, nScanBlocks);
    k_part<<<NBLK, 256, 0, stream>>>(esrc, edst, off, bsums, ebuf, E, NB, chunk);
    k_csr<<<NB, 256, 0, stream>>>(ebuf, off, bsums, rowse, dinv, ssrc, n, NB, E);

    // features + weight prep (k_prep also zeroes sentinel rows of xb/tb)
    k_cvt<<<(n * CH / 4 + 255) / 256, 256, 0, stream>>>(x, dinv, xb, n * CH);
    k_prep<<<(CH * CH + CH * OC + OC + CH + OC + 255) / 256, 256, 0, stream>>>(
        W1, W2, b2, Wfc, bfc, Wt, Wct, bc, xb, tb, n);
    // y = dinv*(sum Xs + self)   (xb -> yb, 128 ch)
    k_agg<<<(n + 3) / 4, 256, 0, stream>>>(xb, rowse, ssrc, dinv, yb, n);
    // t = (dinv*relu(y*W1 + b1)) * Wct   (yb -> tb, 64 ch)
    k_gemm_mfma<<<(n + 127) / 128, 256, 0, stream>>>(yb, Wt, b1, dinv, Wct, tb, n);
    // z = dinv*(sum T + self)   (tb -> xb-as-64ch)
    k_agg64<<<(n + 3) / 4, 256, 0, stream>>>(tb, rowse, ssrc, dinv, xb, n);
    // q = sum-pool(z), cnt via atomics
    k_pool64<<<POOLB, 256, 0, stream>>>(xb, batch, q, cnt, n, npb);
    // out = q/cnt + bc
    k_out<<<(NG * OC + 255) / 256, 256, 0, stream>>>(q, cnt, bc, (float*)d_out);
}

// Round 4
// 307.367 us; speedup vs baseline: 1.7427x; 1.0354x over previous
//
#include <hip/hip_runtime.h>
#include <stdint.h>

#define NN 100000
#define NE 1600000
#define CH 128
#define OC 64
#define NG 512
#define NBLK 256      // partition blocks
#define NBMAX 4096    // max coarse buckets (nodes/256)
#define PADSLACK 1792 // per-bucket ssrc padding slack: 256 nodes * 7

typedef unsigned int uint;
typedef unsigned short ushort;
typedef __attribute__((ext_vector_type(8))) short short8;
typedef __attribute__((ext_vector_type(4))) float floatx4;

__device__ __forceinline__ ushort f2bf(float f) {
    uint u = __float_as_uint(f);
    uint r = u + 0x7fffu + ((u >> 16) & 1u);  // round-to-nearest-even
    return (ushort)(r >> 16);
}
__device__ __forceinline__ float bf_lo(uint g) { return __uint_as_float(g << 16); }
__device__ __forceinline__ float bf_hi(uint g) { return __uint_as_float(g & 0xffff0000u); }

// ---------------- bucket histogram, written bucket-major ----------------
__global__ __launch_bounds__(256) void k_hist(const int* __restrict__ dst,
                                              int* __restrict__ bhT,
                                              int E, int NB, int chunk) {
    __shared__ int h[NBMAX];
    int blk = blockIdx.x, tid = threadIdx.x;
    for (int j = tid; j < NB; j += 256) h[j] = 0;
    __syncthreads();
    int lo = blk * chunk, hi = min(E, lo + chunk);
    for (int i = lo + tid; i < hi; i += 256) atomicAdd(&h[dst[i] >> 8], 1);
    __syncthreads();
    for (int j = tid; j < NB; j += 256) bhT[j * NBLK + blk] = h[j];
}

// ---------------- prefix scan (2-phase; block offsets folded by consumers) ---
__global__ __launch_bounds__(256) void k_scan1(const int* __restrict__ in,
                                               int* __restrict__ excl,
                                               int* __restrict__ bsums, int T) {
    __shared__ int sd[256];
    int tid = threadIdx.x;
    int base = blockIdx.x * 1024 + tid * 4;
    int v[4];
#pragma unroll
    for (int i = 0; i < 4; i++) v[i] = (base + i < T) ? in[base + i] : 0;
    int tsum = v[0] + v[1] + v[2] + v[3];
    int val = tsum;
    sd[tid] = val; __syncthreads();
    for (int off = 1; off < 256; off <<= 1) {
        int t = (tid >= off) ? sd[tid - off] : 0;
        __syncthreads();
        val += t; sd[tid] = val;
        __syncthreads();
    }
    int run = val - tsum;
#pragma unroll
    for (int i = 0; i < 4; i++) {
        if (base + i < T) excl[base + i] = run;
        run += v[i];
    }
    if (tid == 255) bsums[blockIdx.x] = val;
}

__global__ __launch_bounds__(128) void k_scan2(int* __restrict__ bs, int nb) {
    __shared__ int sd[128];
    int tid = threadIdx.x;
    int v = (tid < nb) ? bs[tid] : 0;
    int val = v;
    sd[tid] = val; __syncthreads();
    for (int off = 1; off < 128; off <<= 1) {
        int t = (tid >= off) ? sd[tid - off] : 0;
        __syncthreads();
        val += t; sd[tid] = val;
        __syncthreads();
    }
    if (tid < nb) bs[tid] = val - v;
}

// ------- partition: packed (src<<8)|(dst&255) into per-(bucket,block) segs ----
__global__ __launch_bounds__(256) void k_part(const int* __restrict__ src,
                                              const int* __restrict__ dst,
                                              const int* __restrict__ off,
                                              const int* __restrict__ boff,
                                              int* __restrict__ ebuf,
                                              int E, int NB, int chunk) {
    __shared__ int cur[NBMAX];
    int blk = blockIdx.x, tid = threadIdx.x;
    for (int j = tid; j < NB; j += 256) {
        int idx = j * NBLK + blk;
        cur[j] = off[idx] + boff[idx >> 10];
    }
    __syncthreads();
    int lo = blk * chunk, hi = min(E, lo + chunk);
    for (int i = lo + tid; i < hi; i += 256) {
        int s = src[i], d = dst[i];
        int pos = atomicAdd(&cur[d >> 8], 1);
        ebuf[pos] = (s << 8) | (d & 255);
    }
}

// ------- CSR finalize per bucket: deg, dinv, (start,end), padded scatter -----
// Rows padded to x8 with sentinel node index n (zero feature row). Also emits
// s16[node][16]: the first 16 source slots at FIXED stride so the agg kernels
// can issue source-index loads with zero dependent levels.
__global__ __launch_bounds__(256) void k_csr(const int* __restrict__ ebuf,
                                             const int* __restrict__ off,
                                             const int* __restrict__ boff,
                                             int2* __restrict__ rowse,
                                             float* __restrict__ dinv,
                                             int* __restrict__ ssrc,
                                             int* __restrict__ s16,
                                             int n, int NB, int E) {
    __shared__ int cnt[256], sc[256], cur[256];
    int b = blockIdx.x, tid = threadIdx.x;
    int node0 = b << 8;
    int i0 = b * NBLK;
    int bstart = off[i0] + boff[i0 >> 10];
    int bend = E;
    if (b + 1 < NB) {
        int i1 = (b + 1) * NBLK;
        bend = off[i1] + boff[i1 >> 10];
    }
    // padded ssrc region for this bucket
    int rbeg = bstart + b * PADSLACK;
    int rend = bend + (b + 1) * PADSLACK;
    cnt[tid] = 0;
    __syncthreads();
    for (int i = bstart + tid; i < bend; i += 256)
        atomicAdd(&cnt[ebuf[i] & 255], 1);
    // init whole padded region to sentinel (real edges overwrite below)
    for (int i = rbeg + tid; i < rend; i += 256) ssrc[i] = n;
    __syncthreads();
    int v = cnt[tid];
    int pv = (v + 7) & ~7;        // row padded to multiple of 8
    int val = pv;
    sc[tid] = val; __syncthreads();
    for (int o = 1; o < 256; o <<= 1) {
        int t = (tid >= o) ? sc[tid - o] : 0;
        __syncthreads();
        val += t; sc[tid] = val;
        __syncthreads();
    }
    int excl = val - pv;
    int base = rbeg + excl;
    int node = node0 + tid;
    if (node < n) {
        rowse[node] = make_int2(base, base + pv);
        dinv[node] = rsqrtf((float)v + 1.0f);
    }
    cur[tid] = base;
    __syncthreads();
    for (int i = bstart + tid; i < bend; i += 256) {
        int e = ebuf[i];
        int pos = atomicAdd(&cur[e & 255], 1);
        ssrc[pos] = e >> 8;        // s < 2^23, sign-safe
    }
    __syncthreads();
    // emit fixed-stride first-16 source table
    if (node < n) {
        int kk[16];
#pragma unroll
        for (int k = 0; k < 16; k++) kk[k] = (k < pv) ? ssrc[base + k] : n;
        int4* d4 = (int4*)(s16 + ((size_t)node << 4));
        d4[0] = make_int4(kk[0], kk[1], kk[2], kk[3]);
        d4[1] = make_int4(kk[4], kk[5], kk[6], kk[7]);
        d4[2] = make_int4(kk[8], kk[9], kk[10], kk[11]);
        d4[3] = make_int4(kk[12], kk[13], kk[14], kk[15]);
    }
}

// --- fused cvt + prep: blocks [0,cvtBlocks) do fp32->bf16 with dinv scale;
// --- remaining blocks do weight prep + sentinel-row zeroing.
__global__ __launch_bounds__(256) void k_cvtprep(const float* __restrict__ x,
                                                 const float* __restrict__ dinv,
                                                 ushort* __restrict__ xb,
                                                 const float* __restrict__ W1,
                                                 const float* __restrict__ W2,
                                                 const float* __restrict__ b2,
                                                 const float* __restrict__ Wfc,
                                                 const float* __restrict__ bfc,
                                                 ushort* __restrict__ Wt,
                                                 ushort* __restrict__ Wct,
                                                 float* __restrict__ bc,
                                                 ushort* __restrict__ tb,
                                                 int n, int cvtBlocks) {
    if ((int)blockIdx.x < cvtBlocks) {
        int i = (blockIdx.x * 256 + threadIdx.x) * 4;
        if (i >= n * CH) return;
        float d = dinv[i >> 7];
        float4 v = *(const float4*)(x + i);
        uint2 o;
        o.x = (uint)f2bf(v.x * d) | ((uint)f2bf(v.y * d) << 16);
        o.y = (uint)f2bf(v.z * d) | ((uint)f2bf(v.w * d) << 16);
        *(uint2*)(xb + i) = o;
        return;
    }
    const int T0 = CH * CH;
    const int T1 = T0 + CH * OC;
    const int T2 = T1 + OC;
    const int T3 = T2 + CH;
    const int T4 = T3 + OC;
    int t = ((int)blockIdx.x - cvtBlocks) * 256 + threadIdx.x;
    if (t < T0) {
        int nc = t >> 7, k = t & 127;
        Wt[nc * CH + k] = f2bf(W1[k * CH + nc]);
    } else if (t < T1) {
        int u = t - T0;
        int k = u >> 6, o = u & 63;
        float acc = 0.f;
        for (int j = 0; j < CH; j++) acc += W2[k * CH + j] * Wfc[j * OC + o];
        Wct[o * CH + k] = f2bf(acc);   // [OC][CH] bf16, MFMA B-operand layout
    } else if (t < T2) {
        int o = t - T1;
        float acc = bfc[o];
        for (int j = 0; j < CH; j++) acc += b2[j] * Wfc[j * OC + o];
        bc[o] = acc;
    } else if (t < T3) {
        xb[(size_t)n * CH + (t - T2)] = 0;   // sentinel row, 128ch
    } else if (t < T4) {
        tb[(size_t)n * OC + (t - T3)] = 0;   // sentinel row, 64ch
    }
}

// ------- aggregation (128 ch): quarter-wave per edge, mask-free ------------
// Phase 0: first 16 slots via fixed-stride s16 (zero dependent levels).
// Continuation: slots >=16 via rowse/ssrc. Sentinel rows are exact zeros.
__global__ __launch_bounds__(256) void k_agg(const ushort* __restrict__ Hs,
                                             const int2* __restrict__ rowse,
                                             const int* __restrict__ ssrc,
                                             const int* __restrict__ s16,
                                             const float* __restrict__ dinv,
                                             ushort* __restrict__ out, int n) {
    int wid = (blockIdx.x << 2) | (threadIdx.x >> 6);
    if (wid >= n) return;
    int uw = __builtin_amdgcn_readfirstlane(wid);
    int lane = threadIdx.x & 63;
    int sub = lane >> 4;          // edge slot group
    int li = lane & 15;
    int c = li * 8;               // 8 bf16 channels = 16 B per lane
    // zero-dependency loads: first-16 sources, row extent, self row
    int4 sv4 = *(const int4*)(s16 + ((size_t)uw << 4) + sub * 4);
    int2 se = rowse[uw];
    float a0 = 0.f, a1 = 0.f, a2 = 0.f, a3 = 0.f;
    float a4 = 0.f, a5 = 0.f, a6 = 0.f, a7 = 0.f;
    if (sub == 0) {
        uint4 sv = *(const uint4*)(Hs + ((size_t)uw << 7) + c);
        a0 = bf_lo(sv.x); a1 = bf_hi(sv.x);
        a2 = bf_lo(sv.y); a3 = bf_hi(sv.y);
        a4 = bf_lo(sv.z); a5 = bf_hi(sv.z);
        a6 = bf_lo(sv.w); a7 = bf_hi(sv.w);
    }
    {   // phase 0: sub-group `sub` handles slots 4*sub .. 4*sub+3
        uint4 g0 = *(const uint4*)(Hs + (sv4.x << 7) + c);
        uint4 g1 = *(const uint4*)(Hs + (sv4.y << 7) + c);
        uint4 g2 = *(const uint4*)(Hs + (sv4.z << 7) + c);
        uint4 g3 = *(const uint4*)(Hs + (sv4.w << 7) + c);
        a0 += bf_lo(g0.x); a1 += bf_hi(g0.x);
        a2 += bf_lo(g0.y); a3 += bf_hi(g0.y);
        a4 += bf_lo(g0.z); a5 += bf_hi(g0.z);
        a6 += bf_lo(g0.w); a7 += bf_hi(g0.w);
        a0 += bf_lo(g1.x); a1 += bf_hi(g1.x);
        a2 += bf_lo(g1.y); a3 += bf_hi(g1.y);
        a4 += bf_lo(g1.z); a5 += bf_hi(g1.z);
        a6 += bf_lo(g1.w); a7 += bf_hi(g1.w);
        a0 += bf_lo(g2.x); a1 += bf_hi(g2.x);
        a2 += bf_lo(g2.y); a3 += bf_hi(g2.y);
        a4 += bf_lo(g2.z); a5 += bf_hi(g2.z);
        a6 += bf_lo(g2.w); a7 += bf_hi(g2.w);
        a0 += bf_lo(g3.x); a1 += bf_hi(g3.x);
        a2 += bf_lo(g3.y); a3 += bf_hi(g3.y);
        a4 += bf_lo(g3.z); a5 += bf_hi(g3.z);
        a6 += bf_lo(g3.w); a7 += bf_hi(g3.w);
    }
    int e = se.x + 16, e1 = se.y;
    for (; e + 16 <= e1; e += 16) {
        int s0 = ssrc[e + sub];
        int s1 = ssrc[e + 4 + sub];
        int s2 = ssrc[e + 8 + sub];
        int s3 = ssrc[e + 12 + sub];
        uint4 g0 = *(const uint4*)(Hs + (s0 << 7) + c);
        uint4 g1 = *(const uint4*)(Hs + (s1 << 7) + c);
        uint4 g2 = *(const uint4*)(Hs + (s2 << 7) + c);
        uint4 g3 = *(const uint4*)(Hs + (s3 << 7) + c);
        a0 += bf_lo(g0.x); a1 += bf_hi(g0.x);
        a2 += bf_lo(g0.y); a3 += bf_hi(g0.y);
        a4 += bf_lo(g0.z); a5 += bf_hi(g0.z);
        a6 += bf_lo(g0.w); a7 += bf_hi(g0.w);
        a0 += bf_lo(g1.x); a1 += bf_hi(g1.x);
        a2 += bf_lo(g1.y); a3 += bf_hi(g1.y);
        a4 += bf_lo(g1.z); a5 += bf_hi(g1.z);
        a6 += bf_lo(g1.w); a7 += bf_hi(g1.w);
        a0 += bf_lo(g2.x); a1 += bf_hi(g2.x);
        a2 += bf_lo(g2.y); a3 += bf_hi(g2.y);
        a4 += bf_lo(g2.z); a5 += bf_hi(g2.z);
        a6 += bf_lo(g2.w); a7 += bf_hi(g2.w);
        a0 += bf_lo(g3.x); a1 += bf_hi(g3.x);
        a2 += bf_lo(g3.y); a3 += bf_hi(g3.y);
        a4 += bf_lo(g3.z); a5 += bf_hi(g3.z);
        a6 += bf_lo(g3.w); a7 += bf_hi(g3.w);
    }
    if (e < e1) {                 // exactly 8 remaining (rows padded to x8)
        int s0 = ssrc[e + sub];
        int s1 = ssrc[e + 4 + sub];
        uint4 g0 = *(const uint4*)(Hs + (s0 << 7) + c);
        uint4 g1 = *(const uint4*)(Hs + (s1 << 7) + c);
        a0 += bf_lo(g0.x); a1 += bf_hi(g0.x);
        a2 += bf_lo(g0.y); a3 += bf_hi(g0.y);
        a4 += bf_lo(g0.z); a5 += bf_hi(g0.z);
        a6 += bf_lo(g0.w); a7 += bf_hi(g0.w);
        a0 += bf_lo(g1.x); a1 += bf_hi(g1.x);
        a2 += bf_lo(g1.y); a3 += bf_hi(g1.y);
        a4 += bf_lo(g1.z); a5 += bf_hi(g1.z);
        a6 += bf_lo(g1.w); a7 += bf_hi(g1.w);
    }
    a0 += __shfl_xor(a0, 16); a0 += __shfl_xor(a0, 32);
    a1 += __shfl_xor(a1, 16); a1 += __shfl_xor(a1, 32);
    a2 += __shfl_xor(a2, 16); a2 += __shfl_xor(a2, 32);
    a3 += __shfl_xor(a3, 16); a3 += __shfl_xor(a3, 32);
    a4 += __shfl_xor(a4, 16); a4 += __shfl_xor(a4, 32);
    a5 += __shfl_xor(a5, 16); a5 += __shfl_xor(a5, 32);
    a6 += __shfl_xor(a6, 16); a6 += __shfl_xor(a6, 32);
    a7 += __shfl_xor(a7, 16); a7 += __shfl_xor(a7, 32);
    if (sub == 0) {
        float d = dinv[uw];
        uint4 o;
        o.x = (uint)f2bf(a0 * d) | ((uint)f2bf(a1 * d) << 16);
        o.y = (uint)f2bf(a2 * d) | ((uint)f2bf(a3 * d) << 16);
        o.z = (uint)f2bf(a4 * d) | ((uint)f2bf(a5 * d) << 16);
        o.w = (uint)f2bf(a6 * d) | ((uint)f2bf(a7 * d) << 16);
        *(uint4*)(out + ((size_t)uw << 7) + c) = o;
    }
}

// ------- aggregation (64 ch): eighth-wave per edge, mask-free ---------------
__global__ __launch_bounds__(256) void k_agg64(const ushort* __restrict__ Hs,
                                               const int2* __restrict__ rowse,
                                               const int* __restrict__ ssrc,
                                               const int* __restrict__ s16,
                                               const float* __restrict__ dinv,
                                               ushort* __restrict__ out, int n) {
    int wid = (blockIdx.x << 2) | (threadIdx.x >> 6);
    if (wid >= n) return;
    int uw = __builtin_amdgcn_readfirstlane(wid);
    int lane = threadIdx.x & 63;
    int sub = lane >> 3;          // 8 edge slot groups
    int li = lane & 7;
    int c = li * 8;               // 8 bf16 channels = 16 B per lane
    int2 sv2 = *(const int2*)(s16 + ((size_t)uw << 4) + sub * 2);
    int2 se = rowse[uw];
    float a0 = 0.f, a1 = 0.f, a2 = 0.f, a3 = 0.f;
    float a4 = 0.f, a5 = 0.f, a6 = 0.f, a7 = 0.f;
    if (sub == 0) {
        uint4 sv = *(const uint4*)(Hs + ((size_t)uw << 6) + c);
        a0 = bf_lo(sv.x); a1 = bf_hi(sv.x);
        a2 = bf_lo(sv.y); a3 = bf_hi(sv.y);
        a4 = bf_lo(sv.z); a5 = bf_hi(sv.z);
        a6 = bf_lo(sv.w); a7 = bf_hi(sv.w);
    }
    {   // phase 0: sub-group handles slots 2*sub, 2*sub+1
        uint4 g0 = *(const uint4*)(Hs + (sv2.x << 6) + c);
        uint4 g1 = *(const uint4*)(Hs + (sv2.y << 6) + c);
        a0 += bf_lo(g0.x); a1 += bf_hi(g0.x);
        a2 += bf_lo(g0.y); a3 += bf_hi(g0.y);
        a4 += bf_lo(g0.z); a5 += bf_hi(g0.z);
        a6 += bf_lo(g0.w); a7 += bf_hi(g0.w);
        a0 += bf_lo(g1.x); a1 += bf_hi(g1.x);
        a2 += bf_lo(g1.y); a3 += bf_hi(g1.y);
        a4 += bf_lo(g1.z); a5 += bf_hi(g1.z);
        a6 += bf_lo(g1.w); a7 += bf_hi(g1.w);
    }
    int e = se.x + 16, e1 = se.y;
    for (; e + 16 <= e1; e += 16) {
        int s0 = ssrc[e + sub];
        int s1 = ssrc[e + 8 + sub];
        uint4 g0 = *(const uint4*)(Hs + (s0 << 6) + c);
        uint4 g1 = *(const uint4*)(Hs + (s1 << 6) + c);
        a0 += bf_lo(g0.x); a1 += bf_hi(g0.x);
        a2 += bf_lo(g0.y); a3 += bf_hi(g0.y);
        a4 += bf_lo(g0.z); a5 += bf_hi(g0.z);
        a6 += bf_lo(g0.w); a7 += bf_hi(g0.w);
        a0 += bf_lo(g1.x); a1 += bf_hi(g1.x);
        a2 += bf_lo(g1.y); a3 += bf_hi(g1.y);
        a4 += bf_lo(g1.z); a5 += bf_hi(g1.z);
        a6 += bf_lo(g1.w); a7 += bf_hi(g1.w);
    }
    if (e < e1) {                 // exactly 8 remaining
        int s0 = ssrc[e + sub];
        uint4 g0 = *(const uint4*)(Hs + (s0 << 6) + c);
        a0 += bf_lo(g0.x); a1 += bf_hi(g0.x);
        a2 += bf_lo(g0.y); a3 += bf_hi(g0.y);
        a4 += bf_lo(g0.z); a5 += bf_hi(g0.z);
        a6 += bf_lo(g0.w); a7 += bf_hi(g0.w);
    }
    a0 += __shfl_xor(a0, 8); a0 += __shfl_xor(a0, 16); a0 += __shfl_xor(a0, 32);
    a1 += __shfl_xor(a1, 8); a1 += __shfl_xor(a1, 16); a1 += __shfl_xor(a1, 32);
    a2 += __shfl_xor(a2, 8); a2 += __shfl_xor(a2, 16); a2 += __shfl_xor(a2, 32);
    a3 += __shfl_xor(a3, 8); a3 += __shfl_xor(a3, 16); a3 += __shfl_xor(a3, 32);
    a4 += __shfl_xor(a4, 8); a4 += __shfl_xor(a4, 16); a4 += __shfl_xor(a4, 32);
    a5 += __shfl_xor(a5, 8); a5 += __shfl_xor(a5, 16); a5 += __shfl_xor(a5, 32);
    a6 += __shfl_xor(a6, 8); a6 += __shfl_xor(a6, 16); a6 += __shfl_xor(a6, 32);
    a7 += __shfl_xor(a7, 8); a7 += __shfl_xor(a7, 16); a7 += __shfl_xor(a7, 32);
    if (sub == 0) {
        float d = dinv[uw];
        uint4 o;
        o.x = (uint)f2bf(a0 * d) | ((uint)f2bf(a1 * d) << 16);
        o.y = (uint)f2bf(a2 * d) | ((uint)f2bf(a3 * d) << 16);
        o.z = (uint)f2bf(a4 * d) | ((uint)f2bf(a5 * d) << 16);
        o.w = (uint)f2bf(a6 * d) | ((uint)f2bf(a7 * d) << 16);
        *(uint4*)(out + ((size_t)uw << 6) + c) = o;
    }
}

// ---- T = (dinv*relu(Y*W1 + b1)) * Wct : two MFMA stages, LDS tile reuse ----
__global__ __launch_bounds__(256) void k_gemm_mfma(const ushort* __restrict__ Y,
                                                   const ushort* __restrict__ Wt,
                                                   const float* __restrict__ bias,
                                                   const float* __restrict__ dinv,
                                                   const ushort* __restrict__ Wct,
                                                   ushort* __restrict__ T, int n) {
    __shared__ __align__(16) ushort As[128][136];
    int tid = threadIdx.x;
    int r0 = blockIdx.x * 128;
#pragma unroll
    for (int i = 0; i < 8; i++) {
        int idx = tid + i * 256;
        int row = idx >> 4;
        int c8 = (idx & 15) * 8;
        int r = r0 + row;
        uint4 v = make_uint4(0u, 0u, 0u, 0u);
        if (r < n) v = *(const uint4*)(Y + (size_t)r * CH + c8);
        *(uint4*)&As[row][c8] = v;
    }
    __syncthreads();
    int w = tid >> 6, lane = tid & 63;
    int qm = lane & 15, quad = lane >> 4;
    floatx4 acc[2][8];
#pragma unroll
    for (int mi = 0; mi < 2; mi++)
#pragma unroll
        for (int nt = 0; nt < 8; nt++) acc[mi][nt] = (floatx4){0.f, 0.f, 0.f, 0.f};
#pragma unroll
    for (int ks = 0; ks < 4; ks++) {
        int k0 = ks * 32 + quad * 8;
        short8 va0 = *(const short8*)&As[w * 32 + qm][k0];
        short8 va1 = *(const short8*)&As[w * 32 + 16 + qm][k0];
#pragma unroll
        for (int nt = 0; nt < 8; nt++) {
            short8 b = *(const short8*)(Wt + (nt * 16 + qm) * CH + k0);
            acc[0][nt] = __builtin_amdgcn_mfma_f32_16x16x32_bf16(va0, b, acc[0][nt], 0, 0, 0);
            acc[1][nt] = __builtin_amdgcn_mfma_f32_16x16x32_bf16(va1, b, acc[1][nt], 0, 0, 0);
        }
    }
    // epilogue stage 1: hs = dinv*relu(acc+bias), write bf16 back to own rows
#pragma unroll
    for (int mi = 0; mi < 2; mi++) {
#pragma unroll
        for (int reg = 0; reg < 4; reg++) {
            int lrow = w * 32 + mi * 16 + quad * 4 + reg;
            int r = r0 + lrow;
            float d = (r < n) ? dinv[r] : 0.f;   // pad rows -> exact 0
#pragma unroll
            for (int nt = 0; nt < 8; nt++) {
                int cidx = nt * 16 + qm;
                float val = fmaxf(acc[mi][nt][reg] + bias[cidx], 0.f) * d;
                As[lrow][cidx] = f2bf(val);
            }
        }
    }
    __syncthreads();
    // stage 2: T tile = hs(128x128) * Wct(64x128)^T
    floatx4 acc2[2][4];
#pragma unroll
    for (int mi = 0; mi < 2; mi++)
#pragma unroll
        for (int nt = 0; nt < 4; nt++) acc2[mi][nt] = (floatx4){0.f, 0.f, 0.f, 0.f};
#pragma unroll
    for (int ks = 0; ks < 4; ks++) {
        int k0 = ks * 32 + quad * 8;
        short8 va0 = *(const short8*)&As[w * 32 + qm][k0];
        short8 va1 = *(const short8*)&As[w * 32 + 16 + qm][k0];
#pragma unroll
        for (int nt = 0; nt < 4; nt++) {
            short8 b = *(const short8*)(Wct + (nt * 16 + qm) * CH + k0);
            acc2[0][nt] = __builtin_amdgcn_mfma_f32_16x16x32_bf16(va0, b, acc2[0][nt], 0, 0, 0);
            acc2[1][nt] = __builtin_amdgcn_mfma_f32_16x16x32_bf16(va1, b, acc2[1][nt], 0, 0, 0);
        }
    }
#pragma unroll
    for (int mi = 0; mi < 2; mi++) {
#pragma unroll
        for (int reg = 0; reg < 4; reg++) {
            int r = r0 + w * 32 + mi * 16 + quad * 4 + reg;
            if (r >= n) continue;
#pragma unroll
            for (int nt = 0; nt < 4; nt++)
                T[(size_t)r * OC + nt * 16 + qm] = f2bf(acc2[mi][nt][reg]);
        }
    }
}

// ---- fused pool+out: one block per graph, binary-search node range,
// ---- block-reduce 64 channels, write out = mean + bc directly.
__global__ __launch_bounds__(256) void k_poolout(const ushort* __restrict__ Z,
                                                 const int* __restrict__ batch,
                                                 const float* __restrict__ bc,
                                                 float* __restrict__ out, int n) {
    __shared__ float red[4][OC];
    int g = blockIdx.x;
    // lower_bound(batch, g) and lower_bound(batch, g+1)
    int lo = 0, hi = n;
    while (lo < hi) { int m = (lo + hi) >> 1; if (batch[m] < g) lo = m + 1; else hi = m; }
    int beg = lo;
    hi = n;
    while (lo < hi) { int m = (lo + hi) >> 1; if (batch[m] < g + 1) lo = m + 1; else hi = m; }
    int end = lo;
    int w = threadIdx.x >> 6, lane = threadIdx.x & 63;
    float a = 0.f;
    for (int i = beg + w; i < end; i += 4)
        a += __uint_as_float(((uint)Z[(size_t)i * OC + lane]) << 16);
    red[w][lane] = a;
    __syncthreads();
    if (w == 0) {
        float s = red[0][lane] + red[1][lane] + red[2][lane] + red[3][lane];
        float invc = 1.f / fmaxf((float)(end - beg), 1.f);
        out[g * OC + lane] = s * invc + bc[lane];
    }
}

extern "C" void kernel_launch(void* const* d_in, const int* in_sizes, int n_in,
                              void* d_out, int out_size, void* d_ws, size_t ws_size,
                              hipStream_t stream) {
    const float* x   = (const float*)d_in[0];
    const float* W1  = (const float*)d_in[1];
    const float* b1  = (const float*)d_in[2];
    const float* W2  = (const float*)d_in[3];
    const float* b2  = (const float*)d_in[4];
    const float* Wfc = (const float*)d_in[5];
    const float* bfc = (const float*)d_in[6];
    const int* edges = (const int*)d_in[7];
    const int* batch = (const int*)d_in[8];

    const int n = in_sizes[8];        // 100000
    const int E = in_sizes[7] / 2;    // 1600000
    const int* esrc = edges;
    const int* edst = edges + E;

    const int NB = (n + 255) >> 8;            // 391 coarse buckets
    const int T = NB * NBLK;
    const int chunk = (E + NBLK - 1) / NBLK;

    char* p = (char*)d_ws;
    auto carve = [&](size_t bytes) {
        void* r = (void*)p;
        p += (bytes + 255) & ~(size_t)255;
        return r;
    };
    int*    bhT       = (int*)carve((size_t)T * 4);
    int*    off       = (int*)carve((size_t)T * 4);
    int*    bsums     = (int*)carve(512);
    int*    ebuf      = (int*)carve((size_t)E * 4);
    int2*   rowse     = (int2*)carve((size_t)n * 8);
    float*  dinv      = (float*)carve((size_t)n * 4);
    int*    ssrc      = (int*)carve(((size_t)E + (size_t)NB * PADSLACK + 256) * 4);
    int*    s16       = (int*)carve((size_t)n * 16 * 4);
    ushort* xb        = (ushort*)carve((size_t)(n + 1) * CH * 2);  // +sentinel row
    ushort* yb        = (ushort*)carve((size_t)n * CH * 2);
    ushort* tb        = (ushort*)carve((size_t)(n + 1) * OC * 2);  // +sentinel row
    ushort* Wt        = (ushort*)carve((size_t)CH * CH * 2);
    ushort* Wct       = (ushort*)carve((size_t)OC * CH * 2);
    float*  bc        = (float*)carve((size_t)OC * 4);

    int nScanBlocks = (T + 1023) / 1024;
    int cvtBlocks = (n * CH / 4 + 255) / 256;
    int prepBlocks = (CH * CH + CH * OC + OC + CH + OC + 255) / 256;

    // CSR build (atomic-free global ordering, rows padded to x8 w/ sentinel)
    k_hist<<<NBLK, 256, 0, stream>>>(edst, bhT, E, NB, chunk);
    k_scan1<<<nScanBlocks, 256, 0, stream>>>(bhT, off, bsums, T);
    k_scan2<<<1, 128, 0, stream>>>(bsums, nScanBlocks);
    k_part<<<NBLK, 256, 0, stream>>>(esrc, edst, off, bsums, ebuf, E, NB, chunk);
    k_csr<<<NB, 256, 0, stream>>>(ebuf, off, bsums, rowse, dinv, ssrc, s16, n, NB, E);

    // fused features + weight prep (also zeroes sentinel rows of xb/tb)
    k_cvtprep<<<cvtBlocks + prepBlocks, 256, 0, stream>>>(
        x, dinv, xb, W1, W2, b2, Wfc, bfc, Wt, Wct, bc, tb, n, cvtBlocks);
    // y = dinv*(sum Xs + self)   (xb -> yb, 128 ch)
    k_agg<<<(n + 3) / 4, 256, 0, stream>>>(xb, rowse, ssrc, s16, dinv, yb, n);
    // t = (dinv*relu(y*W1 + b1)) * Wct   (yb -> tb, 64 ch)
    k_gemm_mfma<<<(n + 127) / 128, 256, 0, stream>>>(yb, Wt, b1, dinv, Wct, tb, n);
    // z = dinv*(sum T + self)   (tb -> xb-as-64ch)
    k_agg64<<<(n + 3) / 4, 256, 0, stream>>>(tb, rowse, ssrc, s16, dinv, xb, n);
    // out = mean-pool(z) + bc   (one block per graph, no atomics)
    k_poolout<<<NG, 256, 0, stream>>>(xb, batch, bc, (float*)d_out, n);
}